// Round 6
// baseline (160.336 us; speedup 1.0000x reference)
//
#include <hip/hip_runtime.h>
#include <hip/hip_bf16.h>
#include <math.h>

// ---------------------------------------------------------------------------
// TernaryLeNet5 forward.
// R20: RESUBMIT of R19 unchanged — Round-5 bench failed with "MI355X
// container failed twice" (infra, same as Round 0; no counters, kernel never
// measured). LDS audit of conv3fc (84KB static) passes: gfx950 allows 160KB
// per workgroup; overlay barriers correct.
// R19: from R18 (148.9us). Fuse conv3+fc into conv3fc_kernel (64 blocks x
// 256 thr): block = 16 imgs x all 128 ocs, K-split 13/13/12/12 across 4
// waves (same as R18 conv3), red-sum order identical -> bit-exact. h3 stays
// in LDS (no global round-trip); fc weights staged once per block (64x not
// 1024x); fc1/fc2/softmax inline with identical ascending-k fmaf chains.
// Kills 1 launch+gap, 480KB h3 traffic, 41MB fc-weight re-reads.
// conv12/tern unchanged from R18 to isolate.
// absmax pinned at 0.00390625 -> no f32 reassociation anywhere.
// Known: harness's ~42us ws-poison fill is inside dur_us (uncontrollable);
// top-5 counters show only fills => all our kernels < 42us.
// ---------------------------------------------------------------------------

typedef __attribute__((ext_vector_type(8))) short bf16x8;
typedef __attribute__((ext_vector_type(4))) float f32x4;

// ---- ws layout (float offsets) --------------------------------------------
// pb: pabs[5][16] @0, ps1[5][16] @80, pcnt[5][16] @160
static const size_t OFF_PB    = 0;        // 240 f32
static const size_t OFF_W1B   = 256;      // [32][32] bf16 = 512 f32
static const size_t OFF_W2B   = 1056;     // [64][25][32] bf16 = 25600 f32
static const size_t OFF_W3B   = 26656;    // [128][1600] bf16  = 102400 f32
static const size_t OFF_FW1T  = 129056;   // [120][84] f32, +-1/0
static const size_t OFF_FW2T  = 139136;   // [84][10] f32, +-1/0
static const size_t OFF_P2B   = 139976;   // [1024][1600] bf16 = 819200 f32
// total ~4.3 MB

#define BPT 16   // blocks per tensor in ternarize passes

__device__ __forceinline__ ushort f2bf(float v) {   // RNE float->bf16 bits
    unsigned u = __float_as_uint(v);
    unsigned r = (u + 0x7FFFu + ((u >> 16) & 1u)) >> 16;
    return (ushort)r;
}
__device__ __forceinline__ float bf2f(ushort h) {
    return __uint_as_float((unsigned)h << 16);
}

// tanh via hw exp: 1 - 2e/(1+e), e = exp(-2|x|) in (0,1] -> no overflow.
__device__ __forceinline__ float tanh_fast(float x) {
    float e = __expf(-2.0f * fabsf(x));
    float r = 1.0f - 2.0f * e / (1.0f + e);
    return copysignf(r, x);
}

__device__ __forceinline__ void tensor_select(int tensor,
        const float* w1, const float* w2, const float* w3,
        const float* fw1, const float* fw2,
        const float*& src, int& O, int& K) {
    switch (tensor) {
        case 0: src = w1;  O = 32;  K = 25;   break;
        case 1: src = w2;  O = 64;  K = 800;  break;
        case 2: src = w3;  O = 120; K = 1600; break;
        case 3: src = fw1; O = 84;  K = 120;  break;
        default: src = fw2; O = 10; K = 84;   break;
    }
}

__device__ __forceinline__ float block_sum_256(float v, float* sbuf) {
    #pragma unroll
    for (int off = 32; off > 0; off >>= 1) v += __shfl_down(v, off);
    const int wid = threadIdx.x >> 6;
    if ((threadIdx.x & 63) == 0) sbuf[wid] = v;
    __syncthreads();
    return sbuf[0] + sbuf[1] + sbuf[2] + sbuf[3];
}

// alpha for `tensor` from pass2 partials (redundant per-thread compute)
__device__ __forceinline__ float alpha_of(const float* pb, int tensor) {
    float s1 = 0.f, c = 0.f;
    #pragma unroll
    for (int i = 0; i < BPT; ++i) {
        s1 += pb[80 + tensor * BPT + i];
        c  += pb[160 + tensor * BPT + i];
    }
    return s1 / fmaxf(c, 1.0f);
}

// ---------------------------------------------------------------------------
__global__ __launch_bounds__(256)
void tern_pass1(const float* w1, const float* w2, const float* w3,
                const float* fw1, const float* fw2, float* pb) {
    __shared__ float sbuf[4];
    const int tensor = blockIdx.x / BPT;
    const int blk    = blockIdx.x % BPT;
    const float* src; int O, K;
    tensor_select(tensor, w1, w2, w3, fw1, fw2, src, O, K);
    const int n = O * K;
    float s = 0.f;
    for (int i = blk * 256 + threadIdx.x; i < n; i += BPT * 256)
        s += fabsf(src[i]);
    s = block_sum_256(s, sbuf);
    if (threadIdx.x == 0) pb[tensor * BPT + blk] = s;
}

// pass2: delta from pass1 partials; quantize to +-1/0; write masked partials.
__global__ __launch_bounds__(256)
void tern_pass2(const float* w1, const float* w2, const float* w3,
                const float* fw1, const float* fw2,
                ushort* w1b, ushort* w2b, ushort* w3b,
                float* fw1t, float* fw2t, float* pb) {
    __shared__ float sbuf[4];
    const int tensor = blockIdx.x / BPT;
    const int blk    = blockIdx.x % BPT;
    const float* src; int O, K;
    tensor_select(tensor, w1, w2, w3, fw1, fw2, src, O, K);
    const int n = O * K;
    float tot = 0.f;
    #pragma unroll
    for (int i = 0; i < BPT; ++i) tot += pb[tensor * BPT + i];
    const float delta = 0.7f * tot / (float)n;

    const ushort BP = 0x3F80u, BN = 0xBF80u;   // bf16 +1, -1
    float s1 = 0.f, cnt = 0.f;

    if (tensor == 0) {
        // w1 -> bf16 [oc][32]: k 0..24 = taps, k 25..31 = 0 (pads MFMA K)
        for (int j = blk * 256 + threadIdx.x; j < 1024; j += BPT * 256) {
            const int oc = j >> 5, kk = j & 31;
            ushort qb = 0;
            if (kk < 25) {
                float w = src[oc * 25 + kk];
                float aw = fabsf(w);
                if (aw > delta) { s1 += aw; cnt += 1.f; qb = (w > 0.f) ? BP : BN; }
            }
            w1b[j] = qb;
        }
    } else if (tensor == 2) {
        // w3 -> bf16 [oc][1600] row-linear; zero-fill pad rows 120..127
        for (int i = blk * 256 + threadIdx.x; i < 128 * 1600; i += BPT * 256) {
            ushort qb = 0;
            if (i < n) {
                float w = src[i];
                float aw = fabsf(w);
                if (aw > delta) { s1 += aw; cnt += 1.f; qb = (w > 0.f) ? BP : BN; }
            }
            w3b[i] = qb;
        }
    } else if (tensor == 1) {
        // w2 -> bf16 [oc][tap][ic]; src is [oc][ic][kh][kw]
        for (int i = blk * 256 + threadIdx.x; i < n; i += BPT * 256) {
            float w = src[i];
            float aw = fabsf(w);
            ushort qb = 0;
            if (aw > delta) { s1 += aw; cnt += 1.f; qb = (w > 0.f) ? BP : BN; }
            int oc = i / 800;
            int r  = i - oc * 800;
            int ic = r / 25;
            int tap = r - ic * 25;
            w2b[oc * 800 + tap * 32 + ic] = qb;
        }
    } else {
        float* dst = (tensor == 3) ? fw1t : fw2t;
        for (int i = blk * 256 + threadIdx.x; i < n; i += BPT * 256) {
            float w = src[i];
            float aw = fabsf(w);
            float q = 0.f;
            if (aw > delta) { s1 += aw; cnt += 1.f; q = (w > 0.f) ? 1.f : -1.f; }
            int o = i / K;
            int k = i - o * K;
            dst[k * O + o] = q;      // transpose to [k][O]
        }
    }
    s1 = block_sum_256(s1, sbuf);
    __syncthreads();
    cnt = block_sum_256(cnt, sbuf);
    if (threadIdx.x == 0) {
        pb[80 + tensor * BPT + blk]  = s1;
        pb[160 + tensor * BPT + blk] = cnt;
    }
}

// ---------------------------------------------------------------------------
// conv2 MFMA inner, tap-outer with explicit depth-4 register prefetch of the
// B fragments (w2b, L2-resident). Per-acc tap order 0..24 preserved:
// bit-exact vs non-pipelined version.
#define C2PF 4
__device__ __forceinline__ void conv2_all(
        const ushort* __restrict__ w2b, const ushort* sxt,
        int n0, int mt0, int lane, f32x4 acc[4][2]) {
    const int col = lane & 15, quad = lane >> 4;
    const ushort* abase[4];
    #pragma unroll
    for (int mi = 0; mi < 4; ++mi) {
        int m = (mt0 + mi) * 16 + col;
        m = m < 100 ? m : 99;                     // clamp padding rows
        const int oh = m / 10, ow = m - oh * 10;
        abase[mi] = sxt + (oh * 14 + ow) * 40 + quad * 8;
    }
    const ushort* wb0 = w2b + (size_t)(n0 + col) * 800 + quad * 8;
    const ushort* wb1 = wb0 + 16 * 800;
    bf16x8 pb0[C2PF], pb1[C2PF];
    #pragma unroll
    for (int i = 0; i < C2PF; ++i) {
        pb0[i] = *(const bf16x8*)(wb0 + i * 32);
        pb1[i] = *(const bf16x8*)(wb1 + i * 32);
    }
    #pragma unroll
    for (int tap = 0; tap < 25; ++tap) {
        const int slot = tap & (C2PF - 1);        // static after full unroll
        const bf16x8 b0 = pb0[slot];
        const bf16x8 b1 = pb1[slot];
        if (tap + C2PF < 25) {
            pb0[slot] = *(const bf16x8*)(wb0 + (tap + C2PF) * 32);
            pb1[slot] = *(const bf16x8*)(wb1 + (tap + C2PF) * 32);
        }
        const int kh = tap / 5, kw = tap - kh * 5;
        const int aoff = (kh * 14 + kw) * 40;
        #pragma unroll
        for (int mi = 0; mi < 4; ++mi) {
            bf16x8 af = *(const bf16x8*)(abase[mi] + aoff);
            acc[mi][0] = __builtin_amdgcn_mfma_f32_16x16x32_bf16(af, b0, acc[mi][0], 0, 0, 0);
            acc[mi][1] = __builtin_amdgcn_mfma_f32_16x16x32_bf16(af, b1, acc[mi][1], 0, 0, 0);
        }
    }
}

// ---------------------------------------------------------------------------
// conv12: conv1 MFMA (Z-ordered im2col: A row p = poolblk*4 + sub,
// sub = (oh&1)*2+(ow&1); 3 chunks {17,16,16}, stride-36 A) with the full
// 2x2 pool + alpha/bias/tanh fused into the MFMA epilogue, then conv2 MFMA
// + h/v pool. One image per block, 4 blocks/CU (LDS-pinned).
// LDS: A @0 (19584B, overlaid by hb2 12800B after conv1), sxt @19584
// (15680B), sxb @35264 (2048B), salpha @37312.
__global__ __launch_bounds__(256, 4)
void conv12_kernel(const float* __restrict__ x, const ushort* __restrict__ w1b,
                   const float* __restrict__ b1, const ushort* __restrict__ w2b,
                   const float* __restrict__ b2, const float* __restrict__ pb,
                   ushort* __restrict__ p2b) {
    __shared__ __align__(16) char smem[37328];
    ushort* A      = (ushort*)smem;
    float*  hb2    = (float*) smem;                   // overlays A (post-conv1)
    ushort* sxt    = (ushort*)(smem + 19584);
    ushort* sxb    = (ushort*)(smem + 35264);
    float*  salpha = (float*) (smem + 37312);

    const int n = blockIdx.x;
    const int t = threadIdx.x;
    const int wave = t >> 6, lane = t & 63;
    const int col = lane & 15, quad = lane >> 4;

    bf16x8 B0 = *(const bf16x8*)(w1b + col * 32 + quad * 8);
    bf16x8 B1 = *(const bf16x8*)(w1b + (col + 16) * 32 + quad * 8);
    const float b1a = b1[col];
    const float b1b = b1[col + 16];

    {   // stage x -> bf16 sxb
        float4 v = ((const float4*)(x + (size_t)n * 1024))[t];
        ushort4 q;
        q.x = f2bf(v.x); q.y = f2bf(v.y); q.z = f2bf(v.z); q.w = f2bf(v.w);
        *(ushort4*)(sxb + t * 4) = q;
        if (t == 0) salpha[0] = alpha_of(pb, 0);
        if (t == 1) salpha[1] = alpha_of(pb, 1);
    }
    __syncthreads();

    // ---- conv1: 3 chunks of tiles {17,16,16}, Z-ordered rows ------------
    const float a1 = salpha[0];
    for (int c = 0; c < 3; ++c) {
        const int tbase = (c == 0) ? 0 : (17 + 16 * (c - 1));   // 0,17,33
        const int ct    = (c == 0) ? 17 : 16;
        const int pbase = tbase * 16;
        const int rows  = ct * 16;

        for (int r = t; r < rows; r += 256) {
            const int p   = pbase + r;
            const int pb4 = p >> 2, sub = p & 3;
            const int oh = 2 * (pb4 / 14) + (sub >> 1);
            const int ow = 2 * (pb4 % 14) + (sub & 1);
            ushort v[25];
            #pragma unroll
            for (int kh = 0; kh < 5; ++kh) {
                const ushort* rr = sxb + (oh + kh) * 32 + ow;
                v[kh*5+0]=rr[0]; v[kh*5+1]=rr[1]; v[kh*5+2]=rr[2];
                v[kh*5+3]=rr[3]; v[kh*5+4]=rr[4];
            }
            uint2* arow = (uint2*)(A + r * 36);   // 72B rows: banks 18r%32
            #pragma unroll
            for (int j = 0; j < 6; ++j) {
                uint2 w;
                w.x = (unsigned)v[4*j]   | ((unsigned)v[4*j+1] << 16);
                w.y = (unsigned)v[4*j+2] | ((unsigned)v[4*j+3] << 16);
                arow[j] = w;
            }
            uint2 w6; w6.x = (unsigned)v[24]; w6.y = 0u;
            arow[6] = w6;
            uint2 w7; w7.x = 0u; w7.y = 0u;
            arow[7] = w7;
        }
        __syncthreads();

        for (int tl = wave; tl < ct; tl += 4) {
            const ushort* ap = A + (tl * 16 + col) * 36 + quad * 8;
            ushort4 lo = *(const ushort4*)ap;
            ushort4 hi = *(const ushort4*)(ap + 4);
            bf16x8 af;
            af[0]=(short)lo.x; af[1]=(short)lo.y; af[2]=(short)lo.z; af[3]=(short)lo.w;
            af[4]=(short)hi.x; af[5]=(short)hi.y; af[6]=(short)hi.z; af[7]=(short)hi.w;
            f32x4 z = {};
            f32x4 c0 = __builtin_amdgcn_mfma_f32_16x16x32_bf16(af, B0, z, 0, 0, 0);
            f32x4 c1 = __builtin_amdgcn_mfma_f32_16x16x32_bf16(af, B1, z, 0, 0, 0);
            // quad's 4 C-rows = one 2x2 pool window (subs 0..3).
            // bf16-round the two h-pool maxima first: bit-exact vs the old
            // hb1 round-trip, then v-max, then alpha/bias/tanh.
            const int pos2 = (pbase >> 2) + tl * 4 + quad;
            const float h01 = bf2f(f2bf(fmaxf(c0[0], c0[1])));
            const float h23 = bf2f(f2bf(fmaxf(c0[2], c0[3])));
            sxt[pos2 * 40 + col] =
                f2bf(tanh_fast(fmaf(a1, fmaxf(h01, h23), b1a)));
            const float g01 = bf2f(f2bf(fmaxf(c1[0], c1[1])));
            const float g23 = bf2f(f2bf(fmaxf(c1[2], c1[3])));
            sxt[pos2 * 40 + col + 16] =
                f2bf(tanh_fast(fmaf(a1, fmaxf(g01, g23), b1b)));
        }
        __syncthreads();
    }

    // ---- conv2 MFMA -----------------------------------------------------
    const int n0  = (wave & 1) * 32;
    const int mt0 = (wave >> 1) * 4;
    f32x4 acc2[4][2] = {};
    conv2_all(w2b, sxt, n0, mt0, lane, acc2);

    {   // horizontal pool in-register -> hb2[oc][50] (overlays dead A)
        #pragma unroll
        for (int mi = 0; mi < 4; ++mi) {
            const int mrow = (mt0 + mi) * 16 + quad * 4;
            if (mrow < 100) {
                #pragma unroll
                for (int np = 0; np < 2; ++np) {
                    const int oc = n0 + np * 16 + col;
                    float2 hm;
                    hm.x = fmaxf(acc2[mi][np][0], acc2[mi][np][1]);
                    hm.y = fmaxf(acc2[mi][np][2], acc2[mi][np][3]);
                    *(float2*)(&hb2[oc * 50 + (mrow >> 1)]) = hm;
                }
            }
        }
    }
    __syncthreads();

    const float a2 = salpha[1];
    for (int idx = t; idx < 1600; idx += 256) {
        const int oc = idx / 25, r = idx - oc * 25;
        const int ph = r / 5, pw = r - ph * 5;
        const float* hb = &hb2[oc * 50 + ph * 10 + pw];
        float m = fmaxf(hb[0], hb[5]);
        p2b[(size_t)n * 1600 + idx] = f2bf(tanh_fast(fmaf(a2, m, b2[oc])));
    }
}

// ---------------------------------------------------------------------------
// conv3fc: fused conv3 GEMM + fc1 + fc2 + softmax. 64 blocks x 256 threads;
// block = 16 imgs x 128 ocs (K=1600), K-split 13/13/12/12 over 4 waves and
// red-sum order identical to the old conv3_mfma: bit-exact. h3 kept in LDS;
// fc chains k-ascending identical to old fc_kernel: bit-exact.
// LDS: red 32KB (overlaid by sh4[16][84]+sl[16][10] after h3s built),
// h3s[16][120] 7.7KB, fw1s 40.3KB, fw2s 3.4KB, salpha 12B = ~82KB.
__global__ __launch_bounds__(256)
void conv3fc_kernel(const ushort* __restrict__ p2b, const ushort* __restrict__ w3b,
                    const float* __restrict__ b3, const float* __restrict__ pb,
                    const float* __restrict__ fw1t, const float* __restrict__ fb1,
                    const float* __restrict__ fw2t, const float* __restrict__ fb2,
                    float* __restrict__ out) {
    __shared__ __align__(16) char redmem[32768];     // red[4][64][8][4] f32
    __shared__ __align__(16) float h3s[16][120];
    __shared__ __align__(16) float fw1s[120 * 84];
    __shared__ __align__(16) float fw2s[84 * 10];
    __shared__ float salpha[3];
    float (*red)[64][8][4] = (float (*)[64][8][4])redmem;
    float* sh4 = (float*)redmem;                     // [16][84] overlay
    float* sl  = (float*)(redmem + 16 * 84 * 4);     // [16][10] overlay

    const int t = threadIdx.x;
    const int wave = t >> 6, lane = t & 63;
    const int col = lane & 15, quad = lane >> 4;
    const int img0 = blockIdx.x * 16;

    // stage fc weights (visibility covered by the post-conv3 barrier)
    for (int i = t; i < 2520; i += 256)
        ((float4*)fw1s)[i] = ((const float4*)fw1t)[i];
    if (t < 210) ((float4*)fw2s)[t] = ((const float4*)fw2t)[t];
    if (t == 0) salpha[0] = alpha_of(pb, 2);
    if (t == 1) salpha[1] = alpha_of(pb, 3);
    if (t == 2) salpha[2] = alpha_of(pb, 4);

    // ---- conv3 MFMA: 16 imgs x 128 ocs, K-split over waves --------------
    const int kstart = (wave < 2) ? wave * 13 : 26 + (wave - 2) * 12;  // 0,13,26,38
    const int steps  = (wave < 2) ? 13 : 12;
    const ushort* Abase = p2b + (size_t)(img0 + col) * 1600 + kstart * 32 + quad * 8;
    const ushort* Bbase = w3b + (size_t)col * 1600 + kstart * 32 + quad * 8;

    f32x4 acc[8] = {};
    for (int s = 0; s < steps; ++s) {
        const bf16x8 af = *(const bf16x8*)(Abase + s * 32);
        #pragma unroll
        for (int nt = 0; nt < 8; ++nt) {
            const bf16x8 bf = *(const bf16x8*)(Bbase + (size_t)nt * 16 * 1600 + s * 32);
            acc[nt] = __builtin_amdgcn_mfma_f32_16x16x32_bf16(af, bf, acc[nt], 0, 0, 0);
        }
    }
    #pragma unroll
    for (int nt = 0; nt < 8; ++nt)
        #pragma unroll
        for (int r = 0; r < 4; ++r) red[wave][lane][nt][r] = acc[nt][r];
    __syncthreads();

    // ---- cross-wave reduce + alpha/bias/tanh -> h3s ---------------------
    {
        const float a3 = salpha[0];
        const int l = t & 63, vh = t >> 6;
        const int lcol = l & 15, lquad = l >> 4;
        const int img = lquad * 4 + vh;            // 0..15
        #pragma unroll
        for (int nt = 0; nt < 8; ++nt) {
            const int oc = nt * 16 + lcol;
            if (oc < 120) {
                float s = red[0][l][nt][vh] + red[1][l][nt][vh]
                        + red[2][l][nt][vh] + red[3][l][nt][vh];
                h3s[img][oc] = tanh_fast(fmaf(a3, s, b3[oc]));
            }
        }
    }
    __syncthreads();

    // ---- fc1: 1344 tasks (16 img x 84 oc), k 0..119 ascending -----------
    {
        const float af1 = salpha[1];
        for (int task = t; task < 1344; task += 256) {
            const int img = task / 84, oc = task - img * 84;
            float a = 0.f;
            #pragma unroll 4
            for (int k = 0; k < 120; ++k)
                a = fmaf(fw1s[k * 84 + oc], h3s[img][k], a);
            sh4[img * 84 + oc] = tanh_fast(fmaf(af1, a, fb1[oc]));
        }
    }
    __syncthreads();

    // ---- fc2 + logits ---------------------------------------------------
    if (t < 160) {
        const float af2 = salpha[2];
        const int img = t / 10, oc = t - img * 10;
        float a2 = 0.f;
        #pragma unroll 4
        for (int k = 0; k < 84; ++k)
            a2 = fmaf(fw2s[k * 10 + oc], sh4[img * 84 + k], a2);
        const float lg = fmaf(af2, a2, fb2[oc]);
        sl[img * 10 + oc] = lg;
        out[(size_t)(img0 + img) * 10 + oc] = lg;
    }
    __syncthreads();

    // ---- softmax --------------------------------------------------------
    if (t < 160) {
        const int img = t / 10, oc = t - img * 10;
        float m = -INFINITY;
        #pragma unroll
        for (int i = 0; i < 10; ++i) m = fmaxf(m, sl[img * 10 + i]);
        float s = 0.f;
        #pragma unroll
        for (int i = 0; i < 10; ++i) s += expf(sl[img * 10 + i] - m);
        out[10240 + (size_t)(img0 + img) * 10 + oc] = expf(sl[img * 10 + oc] - m) / s;
    }
}

// ---------------------------------------------------------------------------
extern "C" void kernel_launch(void* const* d_in, const int* in_sizes, int n_in,
                              void* d_out, int out_size, void* d_ws, size_t ws_size,
                              hipStream_t stream) {
    const float* x   = (const float*)d_in[0];
    const float* w1  = (const float*)d_in[1];
    const float* b1  = (const float*)d_in[2];
    const float* w2  = (const float*)d_in[3];
    const float* b2  = (const float*)d_in[4];
    const float* w3  = (const float*)d_in[5];
    const float* b3  = (const float*)d_in[6];
    const float* fw1 = (const float*)d_in[7];
    const float* fb1 = (const float*)d_in[8];
    const float* fw2 = (const float*)d_in[9];
    const float* fb2 = (const float*)d_in[10];

    float* ws = (float*)d_ws;
    float*  pb   = ws + OFF_PB;
    ushort* w1b  = (ushort*)(ws + OFF_W1B);
    ushort* w2b  = (ushort*)(ws + OFF_W2B);
    ushort* w3b  = (ushort*)(ws + OFF_W3B);
    float*  fw1t = ws + OFF_FW1T;
    float*  fw2t = ws + OFF_FW2T;
    ushort* p2b  = (ushort*)(ws + OFF_P2B);
    float*  out  = (float*)d_out;

    tern_pass1<<<5 * BPT, 256, 0, stream>>>(w1, w2, w3, fw1, fw2, pb);
    tern_pass2<<<5 * BPT, 256, 0, stream>>>(w1, w2, w3, fw1, fw2,
                                            w1b, w2b, w3b, fw1t, fw2t, pb);
    conv12_kernel<<<1024, 256, 0, stream>>>(x, w1b, b1, w2b, b2, pb, p2b);
    conv3fc_kernel<<<64, 256, 0, stream>>>(p2b, w3b, b3, pb,
                                           fw1t, fb1, fw2t, fb2, out);
}

// Round 7
// 153.026 us; speedup vs baseline: 1.0478x; 1.0478x over previous
//
#include <hip/hip_runtime.h>
#include <hip/hip_bf16.h>
#include <math.h>

// ---------------------------------------------------------------------------
// TernaryLeNet5 forward.
// R21: from R20 (160.3us; conv3fc=41.4us, Occ 2.46%, 701K bank conflicts,
// 1 wave/SIMD latency-crippled). conv3fc v2:
//  (1) 1024 thr/block (16 waves): wave=(kgroup,ntgroup); identical
//      13/13/12/12 MFMA chains per (nt,kgroup) and identical red-sum order
//      -> bit-exact; 4 waves/SIMD instead of 1.
//  (2) red relaid lane-major [kg][nt][r][lane]: conflict-free (was all-64
//      lanes on one bank).
//  (3) reduce/fc re-indexed for 1024 thr; same ascending-k fmaf chains.
// conv12/tern unchanged. absmax pinned at 0.00390625.
// Known: harness's ~42us ws-poison fill is inside dur_us (uncontrollable).
// ---------------------------------------------------------------------------

typedef __attribute__((ext_vector_type(8))) short bf16x8;
typedef __attribute__((ext_vector_type(4))) float f32x4;

// ---- ws layout (float offsets) --------------------------------------------
// pb: pabs[5][16] @0, ps1[5][16] @80, pcnt[5][16] @160
static const size_t OFF_PB    = 0;        // 240 f32
static const size_t OFF_W1B   = 256;      // [32][32] bf16 = 512 f32
static const size_t OFF_W2B   = 1056;     // [64][25][32] bf16 = 25600 f32
static const size_t OFF_W3B   = 26656;    // [128][1600] bf16  = 102400 f32
static const size_t OFF_FW1T  = 129056;   // [120][84] f32, +-1/0
static const size_t OFF_FW2T  = 139136;   // [84][10] f32, +-1/0
static const size_t OFF_P2B   = 139976;   // [1024][1600] bf16 = 819200 f32
// total ~4.3 MB

#define BPT 16   // blocks per tensor in ternarize passes

__device__ __forceinline__ ushort f2bf(float v) {   // RNE float->bf16 bits
    unsigned u = __float_as_uint(v);
    unsigned r = (u + 0x7FFFu + ((u >> 16) & 1u)) >> 16;
    return (ushort)r;
}
__device__ __forceinline__ float bf2f(ushort h) {
    return __uint_as_float((unsigned)h << 16);
}

// tanh via hw exp: 1 - 2e/(1+e), e = exp(-2|x|) in (0,1] -> no overflow.
__device__ __forceinline__ float tanh_fast(float x) {
    float e = __expf(-2.0f * fabsf(x));
    float r = 1.0f - 2.0f * e / (1.0f + e);
    return copysignf(r, x);
}

__device__ __forceinline__ void tensor_select(int tensor,
        const float* w1, const float* w2, const float* w3,
        const float* fw1, const float* fw2,
        const float*& src, int& O, int& K) {
    switch (tensor) {
        case 0: src = w1;  O = 32;  K = 25;   break;
        case 1: src = w2;  O = 64;  K = 800;  break;
        case 2: src = w3;  O = 120; K = 1600; break;
        case 3: src = fw1; O = 84;  K = 120;  break;
        default: src = fw2; O = 10; K = 84;   break;
    }
}

__device__ __forceinline__ float block_sum_256(float v, float* sbuf) {
    #pragma unroll
    for (int off = 32; off > 0; off >>= 1) v += __shfl_down(v, off);
    const int wid = threadIdx.x >> 6;
    if ((threadIdx.x & 63) == 0) sbuf[wid] = v;
    __syncthreads();
    return sbuf[0] + sbuf[1] + sbuf[2] + sbuf[3];
}

// alpha for `tensor` from pass2 partials (redundant per-thread compute)
__device__ __forceinline__ float alpha_of(const float* pb, int tensor) {
    float s1 = 0.f, c = 0.f;
    #pragma unroll
    for (int i = 0; i < BPT; ++i) {
        s1 += pb[80 + tensor * BPT + i];
        c  += pb[160 + tensor * BPT + i];
    }
    return s1 / fmaxf(c, 1.0f);
}

// ---------------------------------------------------------------------------
__global__ __launch_bounds__(256)
void tern_pass1(const float* w1, const float* w2, const float* w3,
                const float* fw1, const float* fw2, float* pb) {
    __shared__ float sbuf[4];
    const int tensor = blockIdx.x / BPT;
    const int blk    = blockIdx.x % BPT;
    const float* src; int O, K;
    tensor_select(tensor, w1, w2, w3, fw1, fw2, src, O, K);
    const int n = O * K;
    float s = 0.f;
    for (int i = blk * 256 + threadIdx.x; i < n; i += BPT * 256)
        s += fabsf(src[i]);
    s = block_sum_256(s, sbuf);
    if (threadIdx.x == 0) pb[tensor * BPT + blk] = s;
}

// pass2: delta from pass1 partials; quantize to +-1/0; write masked partials.
__global__ __launch_bounds__(256)
void tern_pass2(const float* w1, const float* w2, const float* w3,
                const float* fw1, const float* fw2,
                ushort* w1b, ushort* w2b, ushort* w3b,
                float* fw1t, float* fw2t, float* pb) {
    __shared__ float sbuf[4];
    const int tensor = blockIdx.x / BPT;
    const int blk    = blockIdx.x % BPT;
    const float* src; int O, K;
    tensor_select(tensor, w1, w2, w3, fw1, fw2, src, O, K);
    const int n = O * K;
    float tot = 0.f;
    #pragma unroll
    for (int i = 0; i < BPT; ++i) tot += pb[tensor * BPT + i];
    const float delta = 0.7f * tot / (float)n;

    const ushort BP = 0x3F80u, BN = 0xBF80u;   // bf16 +1, -1
    float s1 = 0.f, cnt = 0.f;

    if (tensor == 0) {
        // w1 -> bf16 [oc][32]: k 0..24 = taps, k 25..31 = 0 (pads MFMA K)
        for (int j = blk * 256 + threadIdx.x; j < 1024; j += BPT * 256) {
            const int oc = j >> 5, kk = j & 31;
            ushort qb = 0;
            if (kk < 25) {
                float w = src[oc * 25 + kk];
                float aw = fabsf(w);
                if (aw > delta) { s1 += aw; cnt += 1.f; qb = (w > 0.f) ? BP : BN; }
            }
            w1b[j] = qb;
        }
    } else if (tensor == 2) {
        // w3 -> bf16 [oc][1600] row-linear; zero-fill pad rows 120..127
        for (int i = blk * 256 + threadIdx.x; i < 128 * 1600; i += BPT * 256) {
            ushort qb = 0;
            if (i < n) {
                float w = src[i];
                float aw = fabsf(w);
                if (aw > delta) { s1 += aw; cnt += 1.f; qb = (w > 0.f) ? BP : BN; }
            }
            w3b[i] = qb;
        }
    } else if (tensor == 1) {
        // w2 -> bf16 [oc][tap][ic]; src is [oc][ic][kh][kw]
        for (int i = blk * 256 + threadIdx.x; i < n; i += BPT * 256) {
            float w = src[i];
            float aw = fabsf(w);
            ushort qb = 0;
            if (aw > delta) { s1 += aw; cnt += 1.f; qb = (w > 0.f) ? BP : BN; }
            int oc = i / 800;
            int r  = i - oc * 800;
            int ic = r / 25;
            int tap = r - ic * 25;
            w2b[oc * 800 + tap * 32 + ic] = qb;
        }
    } else {
        float* dst = (tensor == 3) ? fw1t : fw2t;
        for (int i = blk * 256 + threadIdx.x; i < n; i += BPT * 256) {
            float w = src[i];
            float aw = fabsf(w);
            float q = 0.f;
            if (aw > delta) { s1 += aw; cnt += 1.f; q = (w > 0.f) ? 1.f : -1.f; }
            int o = i / K;
            int k = i - o * K;
            dst[k * O + o] = q;      // transpose to [k][O]
        }
    }
    s1 = block_sum_256(s1, sbuf);
    __syncthreads();
    cnt = block_sum_256(cnt, sbuf);
    if (threadIdx.x == 0) {
        pb[80 + tensor * BPT + blk]  = s1;
        pb[160 + tensor * BPT + blk] = cnt;
    }
}

// ---------------------------------------------------------------------------
// conv2 MFMA inner, tap-outer with explicit depth-4 register prefetch of the
// B fragments (w2b, L2-resident). Per-acc tap order 0..24 preserved:
// bit-exact vs non-pipelined version.
#define C2PF 4
__device__ __forceinline__ void conv2_all(
        const ushort* __restrict__ w2b, const ushort* sxt,
        int n0, int mt0, int lane, f32x4 acc[4][2]) {
    const int col = lane & 15, quad = lane >> 4;
    const ushort* abase[4];
    #pragma unroll
    for (int mi = 0; mi < 4; ++mi) {
        int m = (mt0 + mi) * 16 + col;
        m = m < 100 ? m : 99;                     // clamp padding rows
        const int oh = m / 10, ow = m - oh * 10;
        abase[mi] = sxt + (oh * 14 + ow) * 40 + quad * 8;
    }
    const ushort* wb0 = w2b + (size_t)(n0 + col) * 800 + quad * 8;
    const ushort* wb1 = wb0 + 16 * 800;
    bf16x8 pb0[C2PF], pb1[C2PF];
    #pragma unroll
    for (int i = 0; i < C2PF; ++i) {
        pb0[i] = *(const bf16x8*)(wb0 + i * 32);
        pb1[i] = *(const bf16x8*)(wb1 + i * 32);
    }
    #pragma unroll
    for (int tap = 0; tap < 25; ++tap) {
        const int slot = tap & (C2PF - 1);        // static after full unroll
        const bf16x8 b0 = pb0[slot];
        const bf16x8 b1 = pb1[slot];
        if (tap + C2PF < 25) {
            pb0[slot] = *(const bf16x8*)(wb0 + (tap + C2PF) * 32);
            pb1[slot] = *(const bf16x8*)(wb1 + (tap + C2PF) * 32);
        }
        const int kh = tap / 5, kw = tap - kh * 5;
        const int aoff = (kh * 14 + kw) * 40;
        #pragma unroll
        for (int mi = 0; mi < 4; ++mi) {
            bf16x8 af = *(const bf16x8*)(abase[mi] + aoff);
            acc[mi][0] = __builtin_amdgcn_mfma_f32_16x16x32_bf16(af, b0, acc[mi][0], 0, 0, 0);
            acc[mi][1] = __builtin_amdgcn_mfma_f32_16x16x32_bf16(af, b1, acc[mi][1], 0, 0, 0);
        }
    }
}

// ---------------------------------------------------------------------------
// conv12: conv1 MFMA (Z-ordered im2col: A row p = poolblk*4 + sub,
// sub = (oh&1)*2+(ow&1); 3 chunks {17,16,16}, stride-36 A) with the full
// 2x2 pool + alpha/bias/tanh fused into the MFMA epilogue, then conv2 MFMA
// + h/v pool. One image per block, 4 blocks/CU (LDS-pinned).
// LDS: A @0 (19584B, overlaid by hb2 12800B after conv1), sxt @19584
// (15680B), sxb @35264 (2048B), salpha @37312.
__global__ __launch_bounds__(256, 4)
void conv12_kernel(const float* __restrict__ x, const ushort* __restrict__ w1b,
                   const float* __restrict__ b1, const ushort* __restrict__ w2b,
                   const float* __restrict__ b2, const float* __restrict__ pb,
                   ushort* __restrict__ p2b) {
    __shared__ __align__(16) char smem[37328];
    ushort* A      = (ushort*)smem;
    float*  hb2    = (float*) smem;                   // overlays A (post-conv1)
    ushort* sxt    = (ushort*)(smem + 19584);
    ushort* sxb    = (ushort*)(smem + 35264);
    float*  salpha = (float*) (smem + 37312);

    const int n = blockIdx.x;
    const int t = threadIdx.x;
    const int wave = t >> 6, lane = t & 63;
    const int col = lane & 15, quad = lane >> 4;

    bf16x8 B0 = *(const bf16x8*)(w1b + col * 32 + quad * 8);
    bf16x8 B1 = *(const bf16x8*)(w1b + (col + 16) * 32 + quad * 8);
    const float b1a = b1[col];
    const float b1b = b1[col + 16];

    {   // stage x -> bf16 sxb
        float4 v = ((const float4*)(x + (size_t)n * 1024))[t];
        ushort4 q;
        q.x = f2bf(v.x); q.y = f2bf(v.y); q.z = f2bf(v.z); q.w = f2bf(v.w);
        *(ushort4*)(sxb + t * 4) = q;
        if (t == 0) salpha[0] = alpha_of(pb, 0);
        if (t == 1) salpha[1] = alpha_of(pb, 1);
    }
    __syncthreads();

    // ---- conv1: 3 chunks of tiles {17,16,16}, Z-ordered rows ------------
    const float a1 = salpha[0];
    for (int c = 0; c < 3; ++c) {
        const int tbase = (c == 0) ? 0 : (17 + 16 * (c - 1));   // 0,17,33
        const int ct    = (c == 0) ? 17 : 16;
        const int pbase = tbase * 16;
        const int rows  = ct * 16;

        for (int r = t; r < rows; r += 256) {
            const int p   = pbase + r;
            const int pb4 = p >> 2, sub = p & 3;
            const int oh = 2 * (pb4 / 14) + (sub >> 1);
            const int ow = 2 * (pb4 % 14) + (sub & 1);
            ushort v[25];
            #pragma unroll
            for (int kh = 0; kh < 5; ++kh) {
                const ushort* rr = sxb + (oh + kh) * 32 + ow;
                v[kh*5+0]=rr[0]; v[kh*5+1]=rr[1]; v[kh*5+2]=rr[2];
                v[kh*5+3]=rr[3]; v[kh*5+4]=rr[4];
            }
            uint2* arow = (uint2*)(A + r * 36);   // 72B rows: banks 18r%32
            #pragma unroll
            for (int j = 0; j < 6; ++j) {
                uint2 w;
                w.x = (unsigned)v[4*j]   | ((unsigned)v[4*j+1] << 16);
                w.y = (unsigned)v[4*j+2] | ((unsigned)v[4*j+3] << 16);
                arow[j] = w;
            }
            uint2 w6; w6.x = (unsigned)v[24]; w6.y = 0u;
            arow[6] = w6;
            uint2 w7; w7.x = 0u; w7.y = 0u;
            arow[7] = w7;
        }
        __syncthreads();

        for (int tl = wave; tl < ct; tl += 4) {
            const ushort* ap = A + (tl * 16 + col) * 36 + quad * 8;
            ushort4 lo = *(const ushort4*)ap;
            ushort4 hi = *(const ushort4*)(ap + 4);
            bf16x8 af;
            af[0]=(short)lo.x; af[1]=(short)lo.y; af[2]=(short)lo.z; af[3]=(short)lo.w;
            af[4]=(short)hi.x; af[5]=(short)hi.y; af[6]=(short)hi.z; af[7]=(short)hi.w;
            f32x4 z = {};
            f32x4 c0 = __builtin_amdgcn_mfma_f32_16x16x32_bf16(af, B0, z, 0, 0, 0);
            f32x4 c1 = __builtin_amdgcn_mfma_f32_16x16x32_bf16(af, B1, z, 0, 0, 0);
            // quad's 4 C-rows = one 2x2 pool window (subs 0..3).
            // bf16-round the two h-pool maxima first: bit-exact vs the old
            // hb1 round-trip, then v-max, then alpha/bias/tanh.
            const int pos2 = (pbase >> 2) + tl * 4 + quad;
            const float h01 = bf2f(f2bf(fmaxf(c0[0], c0[1])));
            const float h23 = bf2f(f2bf(fmaxf(c0[2], c0[3])));
            sxt[pos2 * 40 + col] =
                f2bf(tanh_fast(fmaf(a1, fmaxf(h01, h23), b1a)));
            const float g01 = bf2f(f2bf(fmaxf(c1[0], c1[1])));
            const float g23 = bf2f(f2bf(fmaxf(c1[2], c1[3])));
            sxt[pos2 * 40 + col + 16] =
                f2bf(tanh_fast(fmaf(a1, fmaxf(g01, g23), b1b)));
        }
        __syncthreads();
    }

    // ---- conv2 MFMA -----------------------------------------------------
    const int n0  = (wave & 1) * 32;
    const int mt0 = (wave >> 1) * 4;
    f32x4 acc2[4][2] = {};
    conv2_all(w2b, sxt, n0, mt0, lane, acc2);

    {   // horizontal pool in-register -> hb2[oc][50] (overlays dead A)
        #pragma unroll
        for (int mi = 0; mi < 4; ++mi) {
            const int mrow = (mt0 + mi) * 16 + quad * 4;
            if (mrow < 100) {
                #pragma unroll
                for (int np = 0; np < 2; ++np) {
                    const int oc = n0 + np * 16 + col;
                    float2 hm;
                    hm.x = fmaxf(acc2[mi][np][0], acc2[mi][np][1]);
                    hm.y = fmaxf(acc2[mi][np][2], acc2[mi][np][3]);
                    *(float2*)(&hb2[oc * 50 + (mrow >> 1)]) = hm;
                }
            }
        }
    }
    __syncthreads();

    const float a2 = salpha[1];
    for (int idx = t; idx < 1600; idx += 256) {
        const int oc = idx / 25, r = idx - oc * 25;
        const int ph = r / 5, pw = r - ph * 5;
        const float* hb = &hb2[oc * 50 + ph * 10 + pw];
        float m = fmaxf(hb[0], hb[5]);
        p2b[(size_t)n * 1600 + idx] = f2bf(tanh_fast(fmaf(a2, m, b2[oc])));
    }
}

// ---------------------------------------------------------------------------
// conv3fc v2: fused conv3 GEMM + fc1 + fc2 + softmax. 64 blocks x 1024 thr
// (16 waves): wave w = (kgroup = w&3, ntgroup = w>>2); each wave runs the
// SAME 13/13/12/12 MFMA chain per (nt,kgroup) as R18's conv3 (bit-exact),
// covering nt = ntg*2, ntg*2+1. red laid lane-major [kg][nt][r][lane]:
// conflict-free. h3 in LDS; fc chains k-ascending identical: bit-exact.
// LDS: red 32KB (overlaid by sh4[16][84]+sl[16][10] after h3s built),
// h3s[16][120] 7.7KB, fw1s 40.3KB, fw2s 3.4KB = ~84KB, 1 block/CU,
// 4 waves/SIMD.
__global__ __launch_bounds__(1024)
void conv3fc_kernel(const ushort* __restrict__ p2b, const ushort* __restrict__ w3b,
                    const float* __restrict__ b3, const float* __restrict__ pb,
                    const float* __restrict__ fw1t, const float* __restrict__ fb1,
                    const float* __restrict__ fw2t, const float* __restrict__ fb2,
                    float* __restrict__ out) {
    __shared__ __align__(16) char redmem[32768];     // red[4][8][4][64] f32
    __shared__ __align__(16) float h3s[16][120];
    __shared__ __align__(16) float fw1s[120 * 84];
    __shared__ __align__(16) float fw2s[84 * 10];
    __shared__ float salpha[3];
    float (*red)[8][4][64] = (float (*)[8][4][64])redmem;  // [kg][nt][r][lane]
    float* sh4 = (float*)redmem;                     // [16][84] overlay
    float* sl  = (float*)(redmem + 16 * 84 * 4);     // [16][10] overlay

    const int t = threadIdx.x;
    const int wave = t >> 6, lane = t & 63;
    const int col = lane & 15, quad = lane >> 4;
    const int img0 = blockIdx.x * 16;
    const int kg  = wave & 3;       // K-split index (sum order 0..3)
    const int ntg = wave >> 2;      // handles nt = ntg*2, ntg*2+1

    // stage fc weights (visibility covered by the post-conv3 barrier)
    for (int i = t; i < 2520; i += 1024)
        ((float4*)fw1s)[i] = ((const float4*)fw1t)[i];
    if (t < 210) ((float4*)fw2s)[t] = ((const float4*)fw2t)[t];
    if (t == 0) salpha[0] = alpha_of(pb, 2);
    if (t == 1) salpha[1] = alpha_of(pb, 3);
    if (t == 2) salpha[2] = alpha_of(pb, 4);

    // ---- conv3 MFMA: 16 imgs x 2 nt-tiles per wave, K-split over kg -----
    const int kstart = (kg < 2) ? kg * 13 : 26 + (kg - 2) * 12;  // 0,13,26,38
    const int steps  = (kg < 2) ? 13 : 12;
    const ushort* Abase = p2b + (size_t)(img0 + col) * 1600 + kstart * 32 + quad * 8;

    f32x4 acc[2] = {};
    {
        const int nt0 = ntg * 2;
        const ushort* Bb0 = w3b + (size_t)(nt0 * 16 + col) * 1600 + kstart * 32 + quad * 8;
        const ushort* Bb1 = Bb0 + (size_t)16 * 1600;
        for (int s = 0; s < steps; ++s) {
            const bf16x8 af = *(const bf16x8*)(Abase + s * 32);
            const bf16x8 b0 = *(const bf16x8*)(Bb0 + s * 32);
            const bf16x8 b1 = *(const bf16x8*)(Bb1 + s * 32);
            acc[0] = __builtin_amdgcn_mfma_f32_16x16x32_bf16(af, b0, acc[0], 0, 0, 0);
            acc[1] = __builtin_amdgcn_mfma_f32_16x16x32_bf16(af, b1, acc[1], 0, 0, 0);
        }
        #pragma unroll
        for (int j = 0; j < 2; ++j)
            #pragma unroll
            for (int r = 0; r < 4; ++r)
                red[kg][nt0 + j][r][lane] = acc[j][r];
    }
    __syncthreads();

    // ---- cross-wave reduce + alpha/bias/tanh -> h3s ---------------------
    // 2048 outputs (16 img x 128 oc) over 1024 threads, 2 each.
    {
        const float a3 = salpha[0];
        #pragma unroll
        for (int half = 0; half < 2; ++half) {
            const int idx = t + half * 1024;
            const int nt  = idx >> 8;
            const int rem = idx & 255;
            const int vh  = rem >> 6;
            const int l   = rem & 63;
            const int img = ((l >> 4) << 2) + vh;
            const int oc  = (nt << 4) + (l & 15);
            if (oc < 120) {
                float s = red[0][nt][vh][l] + red[1][nt][vh][l]
                        + red[2][nt][vh][l] + red[3][nt][vh][l];
                h3s[img][oc] = tanh_fast(fmaf(a3, s, b3[oc]));
            }
        }
    }
    __syncthreads();

    // ---- fc1: 1344 tasks (16 img x 84 oc), k 0..119 ascending -----------
    {
        const float af1 = salpha[1];
        for (int task = t; task < 1344; task += 1024) {
            const int img = task / 84, oc = task - img * 84;
            float a = 0.f;
            #pragma unroll 4
            for (int k = 0; k < 120; ++k)
                a = fmaf(fw1s[k * 84 + oc], h3s[img][k], a);
            sh4[img * 84 + oc] = tanh_fast(fmaf(af1, a, fb1[oc]));
        }
    }
    __syncthreads();

    // ---- fc2 + logits ---------------------------------------------------
    if (t < 160) {
        const float af2 = salpha[2];
        const int img = t / 10, oc = t - img * 10;
        float a2 = 0.f;
        #pragma unroll 4
        for (int k = 0; k < 84; ++k)
            a2 = fmaf(fw2s[k * 10 + oc], sh4[img * 84 + k], a2);
        const float lg = fmaf(af2, a2, fb2[oc]);
        sl[img * 10 + oc] = lg;
        out[(size_t)(img0 + img) * 10 + oc] = lg;
    }
    __syncthreads();

    // ---- softmax --------------------------------------------------------
    if (t < 160) {
        const int img = t / 10, oc = t - img * 10;
        float m = -INFINITY;
        #pragma unroll
        for (int i = 0; i < 10; ++i) m = fmaxf(m, sl[img * 10 + i]);
        float s = 0.f;
        #pragma unroll
        for (int i = 0; i < 10; ++i) s += expf(sl[img * 10 + i] - m);
        out[10240 + (size_t)(img0 + img) * 10 + oc] = expf(sl[img * 10 + oc] - m) / s;
    }
}

// ---------------------------------------------------------------------------
extern "C" void kernel_launch(void* const* d_in, const int* in_sizes, int n_in,
                              void* d_out, int out_size, void* d_ws, size_t ws_size,
                              hipStream_t stream) {
    const float* x   = (const float*)d_in[0];
    const float* w1  = (const float*)d_in[1];
    const float* b1  = (const float*)d_in[2];
    const float* w2  = (const float*)d_in[3];
    const float* b2  = (const float*)d_in[4];
    const float* w3  = (const float*)d_in[5];
    const float* b3  = (const float*)d_in[6];
    const float* fw1 = (const float*)d_in[7];
    const float* fb1 = (const float*)d_in[8];
    const float* fw2 = (const float*)d_in[9];
    const float* fb2 = (const float*)d_in[10];

    float* ws = (float*)d_ws;
    float*  pb   = ws + OFF_PB;
    ushort* w1b  = (ushort*)(ws + OFF_W1B);
    ushort* w2b  = (ushort*)(ws + OFF_W2B);
    ushort* w3b  = (ushort*)(ws + OFF_W3B);
    float*  fw1t = ws + OFF_FW1T;
    float*  fw2t = ws + OFF_FW2T;
    ushort* p2b  = (ushort*)(ws + OFF_P2B);
    float*  out  = (float*)d_out;

    tern_pass1<<<5 * BPT, 256, 0, stream>>>(w1, w2, w3, fw1, fw2, pb);
    tern_pass2<<<5 * BPT, 256, 0, stream>>>(w1, w2, w3, fw1, fw2,
                                            w1b, w2b, w3b, fw1t, fw2t, pb);
    conv12_kernel<<<1024, 256, 0, stream>>>(x, w1b, b1, w2b, b2, pb, p2b);
    conv3fc_kernel<<<64, 1024, 0, stream>>>(p2b, w3b, b3, pb,
                                            fw1t, fb1, fw2t, fb2, out);
}

// Round 8
// 148.526 us; speedup vs baseline: 1.0795x; 1.0303x over previous
//
#include <hip/hip_runtime.h>
#include <hip/hip_bf16.h>
#include <math.h>

// ---------------------------------------------------------------------------
// TernaryLeNet5 forward.
// R22: from R21 (153.0us; conv3fc v2 fixed, now < fills). conv12 conv1
// rewrite: direct register A-fragment build — each lane gathers its own 8
// taps (K=quad*8..+7) straight from sxb via 8x ds_read_u16 + pack (same
// values, same single MFMA per tile: bit-exact). Eliminates the A im2col
// LDS buffer (19.6KB), the stage/readback phases, and 6 of 10 barriers
// (now: stage sxb -> conv1 -> conv2 -> epilogue, 3 barriers). Pad taps
// (>=25, quad3 j>=1) masked to 0 with woff clamped in-bounds. conv2 and
// conv3fc/tern byte-identical to R21 to isolate.
// absmax pinned at 0.00390625 -> no f32 reassociation anywhere.
// Known: harness's ~41us ws-poison fill is inside dur_us (uncontrollable);
// cross-run drift ~±4us — compare within-run where possible.
// ---------------------------------------------------------------------------

typedef __attribute__((ext_vector_type(8))) short bf16x8;
typedef __attribute__((ext_vector_type(4))) float f32x4;

// ---- ws layout (float offsets) --------------------------------------------
// pb: pabs[5][16] @0, ps1[5][16] @80, pcnt[5][16] @160
static const size_t OFF_PB    = 0;        // 240 f32
static const size_t OFF_W1B   = 256;      // [32][32] bf16 = 512 f32
static const size_t OFF_W2B   = 1056;     // [64][25][32] bf16 = 25600 f32
static const size_t OFF_W3B   = 26656;    // [128][1600] bf16  = 102400 f32
static const size_t OFF_FW1T  = 129056;   // [120][84] f32, +-1/0
static const size_t OFF_FW2T  = 139136;   // [84][10] f32, +-1/0
static const size_t OFF_P2B   = 139976;   // [1024][1600] bf16 = 819200 f32
// total ~4.3 MB

#define BPT 16   // blocks per tensor in ternarize passes

__device__ __forceinline__ ushort f2bf(float v) {   // RNE float->bf16 bits
    unsigned u = __float_as_uint(v);
    unsigned r = (u + 0x7FFFu + ((u >> 16) & 1u)) >> 16;
    return (ushort)r;
}
__device__ __forceinline__ float bf2f(ushort h) {
    return __uint_as_float((unsigned)h << 16);
}

// tanh via hw exp: 1 - 2e/(1+e), e = exp(-2|x|) in (0,1] -> no overflow.
__device__ __forceinline__ float tanh_fast(float x) {
    float e = __expf(-2.0f * fabsf(x));
    float r = 1.0f - 2.0f * e / (1.0f + e);
    return copysignf(r, x);
}

__device__ __forceinline__ void tensor_select(int tensor,
        const float* w1, const float* w2, const float* w3,
        const float* fw1, const float* fw2,
        const float*& src, int& O, int& K) {
    switch (tensor) {
        case 0: src = w1;  O = 32;  K = 25;   break;
        case 1: src = w2;  O = 64;  K = 800;  break;
        case 2: src = w3;  O = 120; K = 1600; break;
        case 3: src = fw1; O = 84;  K = 120;  break;
        default: src = fw2; O = 10; K = 84;   break;
    }
}

__device__ __forceinline__ float block_sum_256(float v, float* sbuf) {
    #pragma unroll
    for (int off = 32; off > 0; off >>= 1) v += __shfl_down(v, off);
    const int wid = threadIdx.x >> 6;
    if ((threadIdx.x & 63) == 0) sbuf[wid] = v;
    __syncthreads();
    return sbuf[0] + sbuf[1] + sbuf[2] + sbuf[3];
}

// alpha for `tensor` from pass2 partials (redundant per-thread compute)
__device__ __forceinline__ float alpha_of(const float* pb, int tensor) {
    float s1 = 0.f, c = 0.f;
    #pragma unroll
    for (int i = 0; i < BPT; ++i) {
        s1 += pb[80 + tensor * BPT + i];
        c  += pb[160 + tensor * BPT + i];
    }
    return s1 / fmaxf(c, 1.0f);
}

// ---------------------------------------------------------------------------
__global__ __launch_bounds__(256)
void tern_pass1(const float* w1, const float* w2, const float* w3,
                const float* fw1, const float* fw2, float* pb) {
    __shared__ float sbuf[4];
    const int tensor = blockIdx.x / BPT;
    const int blk    = blockIdx.x % BPT;
    const float* src; int O, K;
    tensor_select(tensor, w1, w2, w3, fw1, fw2, src, O, K);
    const int n = O * K;
    float s = 0.f;
    for (int i = blk * 256 + threadIdx.x; i < n; i += BPT * 256)
        s += fabsf(src[i]);
    s = block_sum_256(s, sbuf);
    if (threadIdx.x == 0) pb[tensor * BPT + blk] = s;
}

// pass2: delta from pass1 partials; quantize to +-1/0; write masked partials.
__global__ __launch_bounds__(256)
void tern_pass2(const float* w1, const float* w2, const float* w3,
                const float* fw1, const float* fw2,
                ushort* w1b, ushort* w2b, ushort* w3b,
                float* fw1t, float* fw2t, float* pb) {
    __shared__ float sbuf[4];
    const int tensor = blockIdx.x / BPT;
    const int blk    = blockIdx.x % BPT;
    const float* src; int O, K;
    tensor_select(tensor, w1, w2, w3, fw1, fw2, src, O, K);
    const int n = O * K;
    float tot = 0.f;
    #pragma unroll
    for (int i = 0; i < BPT; ++i) tot += pb[tensor * BPT + i];
    const float delta = 0.7f * tot / (float)n;

    const ushort BP = 0x3F80u, BN = 0xBF80u;   // bf16 +1, -1
    float s1 = 0.f, cnt = 0.f;

    if (tensor == 0) {
        // w1 -> bf16 [oc][32]: k 0..24 = taps, k 25..31 = 0 (pads MFMA K)
        for (int j = blk * 256 + threadIdx.x; j < 1024; j += BPT * 256) {
            const int oc = j >> 5, kk = j & 31;
            ushort qb = 0;
            if (kk < 25) {
                float w = src[oc * 25 + kk];
                float aw = fabsf(w);
                if (aw > delta) { s1 += aw; cnt += 1.f; qb = (w > 0.f) ? BP : BN; }
            }
            w1b[j] = qb;
        }
    } else if (tensor == 2) {
        // w3 -> bf16 [oc][1600] row-linear; zero-fill pad rows 120..127
        for (int i = blk * 256 + threadIdx.x; i < 128 * 1600; i += BPT * 256) {
            ushort qb = 0;
            if (i < n) {
                float w = src[i];
                float aw = fabsf(w);
                if (aw > delta) { s1 += aw; cnt += 1.f; qb = (w > 0.f) ? BP : BN; }
            }
            w3b[i] = qb;
        }
    } else if (tensor == 1) {
        // w2 -> bf16 [oc][tap][ic]; src is [oc][ic][kh][kw]
        for (int i = blk * 256 + threadIdx.x; i < n; i += BPT * 256) {
            float w = src[i];
            float aw = fabsf(w);
            ushort qb = 0;
            if (aw > delta) { s1 += aw; cnt += 1.f; qb = (w > 0.f) ? BP : BN; }
            int oc = i / 800;
            int r  = i - oc * 800;
            int ic = r / 25;
            int tap = r - ic * 25;
            w2b[oc * 800 + tap * 32 + ic] = qb;
        }
    } else {
        float* dst = (tensor == 3) ? fw1t : fw2t;
        for (int i = blk * 256 + threadIdx.x; i < n; i += BPT * 256) {
            float w = src[i];
            float aw = fabsf(w);
            float q = 0.f;
            if (aw > delta) { s1 += aw; cnt += 1.f; q = (w > 0.f) ? 1.f : -1.f; }
            int o = i / K;
            int k = i - o * K;
            dst[k * O + o] = q;      // transpose to [k][O]
        }
    }
    s1 = block_sum_256(s1, sbuf);
    __syncthreads();
    cnt = block_sum_256(cnt, sbuf);
    if (threadIdx.x == 0) {
        pb[80 + tensor * BPT + blk]  = s1;
        pb[160 + tensor * BPT + blk] = cnt;
    }
}

// ---------------------------------------------------------------------------
// conv2 MFMA inner, tap-outer with explicit depth-4 register prefetch of the
// B fragments (w2b, L2-resident). Per-acc tap order 0..24 preserved:
// bit-exact vs non-pipelined version.
#define C2PF 4
__device__ __forceinline__ void conv2_all(
        const ushort* __restrict__ w2b, const ushort* sxt,
        int n0, int mt0, int lane, f32x4 acc[4][2]) {
    const int col = lane & 15, quad = lane >> 4;
    const ushort* abase[4];
    #pragma unroll
    for (int mi = 0; mi < 4; ++mi) {
        int m = (mt0 + mi) * 16 + col;
        m = m < 100 ? m : 99;                     // clamp padding rows
        const int oh = m / 10, ow = m - oh * 10;
        abase[mi] = sxt + (oh * 14 + ow) * 40 + quad * 8;
    }
    const ushort* wb0 = w2b + (size_t)(n0 + col) * 800 + quad * 8;
    const ushort* wb1 = wb0 + 16 * 800;
    bf16x8 pb0[C2PF], pb1[C2PF];
    #pragma unroll
    for (int i = 0; i < C2PF; ++i) {
        pb0[i] = *(const bf16x8*)(wb0 + i * 32);
        pb1[i] = *(const bf16x8*)(wb1 + i * 32);
    }
    #pragma unroll
    for (int tap = 0; tap < 25; ++tap) {
        const int slot = tap & (C2PF - 1);        // static after full unroll
        const bf16x8 b0 = pb0[slot];
        const bf16x8 b1 = pb1[slot];
        if (tap + C2PF < 25) {
            pb0[slot] = *(const bf16x8*)(wb0 + (tap + C2PF) * 32);
            pb1[slot] = *(const bf16x8*)(wb1 + (tap + C2PF) * 32);
        }
        const int kh = tap / 5, kw = tap - kh * 5;
        const int aoff = (kh * 14 + kw) * 40;
        #pragma unroll
        for (int mi = 0; mi < 4; ++mi) {
            bf16x8 af = *(const bf16x8*)(abase[mi] + aoff);
            acc[mi][0] = __builtin_amdgcn_mfma_f32_16x16x32_bf16(af, b0, acc[mi][0], 0, 0, 0);
            acc[mi][1] = __builtin_amdgcn_mfma_f32_16x16x32_bf16(af, b1, acc[mi][1], 0, 0, 0);
        }
    }
}

// ---------------------------------------------------------------------------
// conv12: conv1 MFMA with DIRECT register A-build (no im2col staging):
// lane (col,quad) of tile tl gathers taps quad*8..+7 of position
// p = tl*16+col from sxb (8x ds_read_u16 + pack), masks pad taps, one
// 16x16x32 MFMA per oc-half; 2x2 pool + alpha/bias/tanh fused in epilogue
// (Z-order: quad's 4 C-rows = one pool window). Then conv2 MFMA + h/v pool.
// One image per block, 4 blocks/CU. 3 barriers total.
// LDS: sxt @0 (15680B), hb2 @15680 (12800B), sxb @28480 (2048B),
// salpha @30528 -> ~30.5KB.
__global__ __launch_bounds__(256, 4)
void conv12_kernel(const float* __restrict__ x, const ushort* __restrict__ w1b,
                   const float* __restrict__ b1, const ushort* __restrict__ w2b,
                   const float* __restrict__ b2, const float* __restrict__ pb,
                   ushort* __restrict__ p2b) {
    __shared__ __align__(16) char smem[30544];
    ushort* sxt    = (ushort*)smem;
    float*  hb2    = (float*) (smem + 15680);
    ushort* sxb    = (ushort*)(smem + 28480);
    float*  salpha = (float*) (smem + 30528);

    const int n = blockIdx.x;
    const int t = threadIdx.x;
    const int wave = t >> 6, lane = t & 63;
    const int col = lane & 15, quad = lane >> 4;

    bf16x8 B0 = *(const bf16x8*)(w1b + col * 32 + quad * 8);
    bf16x8 B1 = *(const bf16x8*)(w1b + (col + 16) * 32 + quad * 8);
    const float b1a = b1[col];
    const float b1b = b1[col + 16];

    {   // stage x -> bf16 sxb
        float4 v = ((const float4*)(x + (size_t)n * 1024))[t];
        ushort4 q;
        q.x = f2bf(v.x); q.y = f2bf(v.y); q.z = f2bf(v.z); q.w = f2bf(v.w);
        *(ushort4*)(sxb + t * 4) = q;
        if (t == 0) salpha[0] = alpha_of(pb, 0);
        if (t == 1) salpha[1] = alpha_of(pb, 1);
    }
    __syncthreads();

    // ---- conv1: 49 tiles, direct A-build, Z-ordered positions -----------
    {
        const float a1 = salpha[0];
        // per-lane constants
        const int sub  = col & 3;
        const int colq = col >> 2;
        const int soff = ((sub >> 1) << 5) + (sub & 1);   // oh,ow sub-offset
        int woff[8];
        #pragma unroll
        for (int j = 0; j < 8; ++j) {
            const int tap = quad * 8 + j;
            woff[j] = (tap < 25) ? ((tap / 5) << 5) + (tap % 5) : 0;
        }
        const unsigned kmask = (quad == 3) ? 0u : 0xFFFFFFFFu;

        for (int tl = wave; tl < 49; tl += 4) {
            const int pb4 = tl * 4 + colq;                // pool block 0..195
            const int bh  = (pb4 * 4682) >> 16;           // pb4 / 14
            const int bw  = pb4 - bh * 14;
            const int base = (bh << 6) + (bw << 1) + soff; // oh*32 + ow
            unsigned v0 = sxb[base + woff[0]];
            unsigned v1 = sxb[base + woff[1]] & kmask;
            unsigned v2 = sxb[base + woff[2]] & kmask;
            unsigned v3 = sxb[base + woff[3]] & kmask;
            unsigned v4 = sxb[base + woff[4]] & kmask;
            unsigned v5 = sxb[base + woff[5]] & kmask;
            unsigned v6 = sxb[base + woff[6]] & kmask;
            unsigned v7 = sxb[base + woff[7]] & kmask;
            uint4 u;
            u.x = v0 | (v1 << 16);
            u.y = v2 | (v3 << 16);
            u.z = v4 | (v5 << 16);
            u.w = v6 | (v7 << 16);
            const bf16x8 af = *(const bf16x8*)&u;
            f32x4 z = {};
            f32x4 c0 = __builtin_amdgcn_mfma_f32_16x16x32_bf16(af, B0, z, 0, 0, 0);
            f32x4 c1 = __builtin_amdgcn_mfma_f32_16x16x32_bf16(af, B1, z, 0, 0, 0);
            // quad's 4 C-rows = one 2x2 pool window (subs 0..3).
            // bf16-round the two h-pool maxima first (bit-exact vs the old
            // hb1 round-trip), then v-max, then alpha/bias/tanh.
            const int pos2 = tl * 4 + quad;
            const float h01 = bf2f(f2bf(fmaxf(c0[0], c0[1])));
            const float h23 = bf2f(f2bf(fmaxf(c0[2], c0[3])));
            sxt[pos2 * 40 + col] =
                f2bf(tanh_fast(fmaf(a1, fmaxf(h01, h23), b1a)));
            const float g01 = bf2f(f2bf(fmaxf(c1[0], c1[1])));
            const float g23 = bf2f(f2bf(fmaxf(c1[2], c1[3])));
            sxt[pos2 * 40 + col + 16] =
                f2bf(tanh_fast(fmaf(a1, fmaxf(g01, g23), b1b)));
        }
    }
    __syncthreads();

    // ---- conv2 MFMA -----------------------------------------------------
    const int n0  = (wave & 1) * 32;
    const int mt0 = (wave >> 1) * 4;
    f32x4 acc2[4][2] = {};
    conv2_all(w2b, sxt, n0, mt0, lane, acc2);

    {   // horizontal pool in-register -> hb2[oc][50]
        #pragma unroll
        for (int mi = 0; mi < 4; ++mi) {
            const int mrow = (mt0 + mi) * 16 + quad * 4;
            if (mrow < 100) {
                #pragma unroll
                for (int np = 0; np < 2; ++np) {
                    const int oc = n0 + np * 16 + col;
                    float2 hm;
                    hm.x = fmaxf(acc2[mi][np][0], acc2[mi][np][1]);
                    hm.y = fmaxf(acc2[mi][np][2], acc2[mi][np][3]);
                    *(float2*)(&hb2[oc * 50 + (mrow >> 1)]) = hm;
                }
            }
        }
    }
    __syncthreads();

    const float a2 = salpha[1];
    for (int idx = t; idx < 1600; idx += 256) {
        const int oc = idx / 25, r = idx - oc * 25;
        const int ph = r / 5, pw = r - ph * 5;
        const float* hb = &hb2[oc * 50 + ph * 10 + pw];
        float m = fmaxf(hb[0], hb[5]);
        p2b[(size_t)n * 1600 + idx] = f2bf(tanh_fast(fmaf(a2, m, b2[oc])));
    }
}

// ---------------------------------------------------------------------------
// conv3fc v2: fused conv3 GEMM + fc1 + fc2 + softmax. 64 blocks x 1024 thr
// (16 waves): wave w = (kgroup = w&3, ntgroup = w>>2); each wave runs the
// SAME 13/13/12/12 MFMA chain per (nt,kgroup) as R18's conv3 (bit-exact),
// covering nt = ntg*2, ntg*2+1. red laid lane-major [kg][nt][r][lane]:
// conflict-free. h3 in LDS; fc chains k-ascending identical: bit-exact.
__global__ __launch_bounds__(1024)
void conv3fc_kernel(const ushort* __restrict__ p2b, const ushort* __restrict__ w3b,
                    const float* __restrict__ b3, const float* __restrict__ pb,
                    const float* __restrict__ fw1t, const float* __restrict__ fb1,
                    const float* __restrict__ fw2t, const float* __restrict__ fb2,
                    float* __restrict__ out) {
    __shared__ __align__(16) char redmem[32768];     // red[4][8][4][64] f32
    __shared__ __align__(16) float h3s[16][120];
    __shared__ __align__(16) float fw1s[120 * 84];
    __shared__ __align__(16) float fw2s[84 * 10];
    __shared__ float salpha[3];
    float (*red)[8][4][64] = (float (*)[8][4][64])redmem;  // [kg][nt][r][lane]
    float* sh4 = (float*)redmem;                     // [16][84] overlay
    float* sl  = (float*)(redmem + 16 * 84 * 4);     // [16][10] overlay

    const int t = threadIdx.x;
    const int wave = t >> 6, lane = t & 63;
    const int col = lane & 15, quad = lane >> 4;
    const int img0 = blockIdx.x * 16;
    const int kg  = wave & 3;       // K-split index (sum order 0..3)
    const int ntg = wave >> 2;      // handles nt = ntg*2, ntg*2+1

    // stage fc weights (visibility covered by the post-conv3 barrier)
    for (int i = t; i < 2520; i += 1024)
        ((float4*)fw1s)[i] = ((const float4*)fw1t)[i];
    if (t < 210) ((float4*)fw2s)[t] = ((const float4*)fw2t)[t];
    if (t == 0) salpha[0] = alpha_of(pb, 2);
    if (t == 1) salpha[1] = alpha_of(pb, 3);
    if (t == 2) salpha[2] = alpha_of(pb, 4);

    // ---- conv3 MFMA: 16 imgs x 2 nt-tiles per wave, K-split over kg -----
    const int kstart = (kg < 2) ? kg * 13 : 26 + (kg - 2) * 12;  // 0,13,26,38
    const int steps  = (kg < 2) ? 13 : 12;
    const ushort* Abase = p2b + (size_t)(img0 + col) * 1600 + kstart * 32 + quad * 8;

    f32x4 acc[2] = {};
    {
        const int nt0 = ntg * 2;
        const ushort* Bb0 = w3b + (size_t)(nt0 * 16 + col) * 1600 + kstart * 32 + quad * 8;
        const ushort* Bb1 = Bb0 + (size_t)16 * 1600;
        for (int s = 0; s < steps; ++s) {
            const bf16x8 af = *(const bf16x8*)(Abase + s * 32);
            const bf16x8 b0 = *(const bf16x8*)(Bb0 + s * 32);
            const bf16x8 b1 = *(const bf16x8*)(Bb1 + s * 32);
            acc[0] = __builtin_amdgcn_mfma_f32_16x16x32_bf16(af, b0, acc[0], 0, 0, 0);
            acc[1] = __builtin_amdgcn_mfma_f32_16x16x32_bf16(af, b1, acc[1], 0, 0, 0);
        }
        #pragma unroll
        for (int j = 0; j < 2; ++j)
            #pragma unroll
            for (int r = 0; r < 4; ++r)
                red[kg][nt0 + j][r][lane] = acc[j][r];
    }
    __syncthreads();

    // ---- cross-wave reduce + alpha/bias/tanh -> h3s ---------------------
    // 2048 outputs (16 img x 128 oc) over 1024 threads, 2 each.
    {
        const float a3 = salpha[0];
        #pragma unroll
        for (int half = 0; half < 2; ++half) {
            const int idx = t + half * 1024;
            const int nt  = idx >> 8;
            const int rem = idx & 255;
            const int vh  = rem >> 6;
            const int l   = rem & 63;
            const int img = ((l >> 4) << 2) + vh;
            const int oc  = (nt << 4) + (l & 15);
            if (oc < 120) {
                float s = red[0][nt][vh][l] + red[1][nt][vh][l]
                        + red[2][nt][vh][l] + red[3][nt][vh][l];
                h3s[img][oc] = tanh_fast(fmaf(a3, s, b3[oc]));
            }
        }
    }
    __syncthreads();

    // ---- fc1: 1344 tasks (16 img x 84 oc), k 0..119 ascending -----------
    {
        const float af1 = salpha[1];
        for (int task = t; task < 1344; task += 1024) {
            const int img = task / 84, oc = task - img * 84;
            float a = 0.f;
            #pragma unroll 4
            for (int k = 0; k < 120; ++k)
                a = fmaf(fw1s[k * 84 + oc], h3s[img][k], a);
            sh4[img * 84 + oc] = tanh_fast(fmaf(af1, a, fb1[oc]));
        }
    }
    __syncthreads();

    // ---- fc2 + logits ---------------------------------------------------
    if (t < 160) {
        const float af2 = salpha[2];
        const int img = t / 10, oc = t - img * 10;
        float a2 = 0.f;
        #pragma unroll 4
        for (int k = 0; k < 84; ++k)
            a2 = fmaf(fw2s[k * 10 + oc], sh4[img * 84 + k], a2);
        const float lg = fmaf(af2, a2, fb2[oc]);
        sl[img * 10 + oc] = lg;
        out[(size_t)(img0 + img) * 10 + oc] = lg;
    }
    __syncthreads();

    // ---- softmax --------------------------------------------------------
    if (t < 160) {
        const int img = t / 10, oc = t - img * 10;
        float m = -INFINITY;
        #pragma unroll
        for (int i = 0; i < 10; ++i) m = fmaxf(m, sl[img * 10 + i]);
        float s = 0.f;
        #pragma unroll
        for (int i = 0; i < 10; ++i) s += expf(sl[img * 10 + i] - m);
        out[10240 + (size_t)(img0 + img) * 10 + oc] = expf(sl[img * 10 + oc] - m) / s;
    }
}

// ---------------------------------------------------------------------------
extern "C" void kernel_launch(void* const* d_in, const int* in_sizes, int n_in,
                              void* d_out, int out_size, void* d_ws, size_t ws_size,
                              hipStream_t stream) {
    const float* x   = (const float*)d_in[0];
    const float* w1  = (const float*)d_in[1];
    const float* b1  = (const float*)d_in[2];
    const float* w2  = (const float*)d_in[3];
    const float* b2  = (const float*)d_in[4];
    const float* w3  = (const float*)d_in[5];
    const float* b3  = (const float*)d_in[6];
    const float* fw1 = (const float*)d_in[7];
    const float* fb1 = (const float*)d_in[8];
    const float* fw2 = (const float*)d_in[9];
    const float* fb2 = (const float*)d_in[10];

    float* ws = (float*)d_ws;
    float*  pb   = ws + OFF_PB;
    ushort* w1b  = (ushort*)(ws + OFF_W1B);
    ushort* w2b  = (ushort*)(ws + OFF_W2B);
    ushort* w3b  = (ushort*)(ws + OFF_W3B);
    float*  fw1t = ws + OFF_FW1T;
    float*  fw2t = ws + OFF_FW2T;
    ushort* p2b  = (ushort*)(ws + OFF_P2B);
    float*  out  = (float*)d_out;

    tern_pass1<<<5 * BPT, 256, 0, stream>>>(w1, w2, w3, fw1, fw2, pb);
    tern_pass2<<<5 * BPT, 256, 0, stream>>>(w1, w2, w3, fw1, fw2,
                                            w1b, w2b, w3b, fw1t, fw2t, pb);
    conv12_kernel<<<1024, 256, 0, stream>>>(x, w1b, b1, w2b, b2, pb, p2b);
    conv3fc_kernel<<<64, 1024, 0, stream>>>(p2b, w3b, b3, pb,
                                            fw1t, fb1, fw2t, fb2, out);
}